// Round 7
// baseline (210.403 us; speedup 1.0000x reference)
//
#include <hip/hip_runtime.h>
#include <stdint.h>

#define BB 16
#define TT 4096
#define CC 8
#define FF 64
#define KW 11
#define LL 4096

#define L2E 1.442695040888963f
#define NCONV (BB * (TT / 64))   // 1024 conv blocks

typedef __attribute__((ext_vector_type(8))) short short8;
typedef __attribute__((ext_vector_type(16))) float floatx16;

// exp(conv+BN) staging buffer — device global (d_ws capacity unknown; 16.8 MB)
__device__ float e_buf[(size_t)BB * TT * FF];

__device__ __forceinline__ unsigned short f2b(float f) {
    union { float f; uint32_t i; } v; v.f = f;
    uint32_t x = v.i;
    return (unsigned short)((x + 0x7fffu + ((x >> 16) & 1u)) >> 16);  // RNE
}
__device__ __forceinline__ float b2f(unsigned short u) {
    union { uint32_t i; float f; } v; v.i = ((uint32_t)u) << 16; return v.f;
}

#define DOT8(acc, ra, rb, wp) \
    acc = fmaf(ra.x, (wp)[0], acc); acc = fmaf(ra.y, (wp)[1], acc); \
    acc = fmaf(ra.z, (wp)[2], acc); acc = fmaf(ra.w, (wp)[3], acc); \
    acc = fmaf(rb.x, (wp)[4], acc); acc = fmaf(rb.y, (wp)[5], acc); \
    acc = fmaf(rb.z, (wp)[6], acc); acc = fmaf(rb.w, (wp)[7], acc);

// ---------------- Kernel 1 (fused): blocks [0,NCONV): conv1d+BN+exp -> e_buf +
// sumexp. blocks [NCONV, NCONV+1024): W fp32 -> Whi/Wlo bf16 planes
// (fragment-linear [ltile 128][kf 4][half 2][ln 32][j 8]).
// Conv uses a rolling 4-output window: 14 row-reads per 4 outputs (vs 44).
__global__ __launch_bounds__(256) void k_convsplit(
        const float* __restrict__ x, const float* __restrict__ cw,
        const float* __restrict__ cb, const float* __restrict__ gm,
        const float* __restrict__ bt, const float* __restrict__ mn,
        const float* __restrict__ vr, const float* __restrict__ dw,
        unsigned short* __restrict__ Wt, float* __restrict__ sumexp) {
    if (blockIdx.x >= NCONV) {
        // ---- W split part (no LDS, no barriers) ----
        const int idx  = (blockIdx.x - NCONV) * 256 + threadIdx.x;   // 262144
        const int j    = idx & 7;
        const int ln   = (idx >> 3) & 31;
        const int half = (idx >> 8) & 1;
        const int kf   = (idx >> 9) & 3;
        const int lt   = idx >> 11;
        const int l = lt * 32 + ln;
        const int k = kf * 16 + half * 8 + j;
        const float v = dw[(size_t)k * LL + l];
        const unsigned short hi = f2b(v);
        const unsigned short lo = f2b(v - b2f(hi));
        Wt[idx] = hi;
        Wt[262144 + idx] = lo;
        return;
    }
    // ---- conv part ----
    __shared__ __align__(16) float xsm[(64 + KW - 1) * CC];   // 592 floats
    __shared__ float red[4 * FF];
    const int tid = threadIdx.x;
    const int b  = blockIdx.x / (TT / 64);
    const int t0 = (blockIdx.x % (TT / 64)) * 64;
    const int f = tid & 63, ts = tid >> 6;

    float wreg[KW * CC];
#pragma unroll
    for (int kc = 0; kc < KW * CC; ++kc) wreg[kc] = cw[kc * FF + f];

    for (int i = tid; i < (64 + KW - 1) * CC; i += 256) {
        int row = i >> 3, c = i & 7;
        int t = t0 - (KW / 2) + row;
        xsm[i] = (t >= 0 && t < TT) ? x[((size_t)b * TT + t) * CC + c] : 0.0f;
    }
    const float s  = gm[f] * rsqrtf(vr[f] + 1e-3f);
    const float bb = bt[f] + (cb[f] - mn[f]) * s;
    const float s2 = s * L2E, b2 = bb * L2E;   // exp(z) = exp2(z*log2e)
    __syncthreads();

    float* eb = e_buf + ((size_t)b * TT + t0) * FF + f;
    const float4* xv = (const float4*)xsm;
    float esum = 0.f;
#pragma unroll 1
    for (int c = 0; c < 4; ++c) {
        const int tb = c * 16 + ts * 4;   // 4 consecutive outputs tb..tb+3
        float a0 = 0.f, a1 = 0.f, a2 = 0.f, a3 = 0.f;
#pragma unroll
        for (int k = 0; k < KW + 3; ++k) {   // rows tb..tb+13
            const float4 ra = xv[(tb + k) * 2];
            const float4 rb = xv[(tb + k) * 2 + 1];
            if (k <= 10)           { DOT8(a0, ra, rb, wreg + k * 8); }
            if (k >= 1 && k <= 11) { DOT8(a1, ra, rb, wreg + (k - 1) * 8); }
            if (k >= 2 && k <= 12) { DOT8(a2, ra, rb, wreg + (k - 2) * 8); }
            if (k >= 3)            { DOT8(a3, ra, rb, wreg + (k - 3) * 8); }
        }
        float e0 = __builtin_amdgcn_exp2f(fmaf(a0, s2, b2));
        float e1 = __builtin_amdgcn_exp2f(fmaf(a1, s2, b2));
        float e2 = __builtin_amdgcn_exp2f(fmaf(a2, s2, b2));
        float e3 = __builtin_amdgcn_exp2f(fmaf(a3, s2, b2));
        eb[(tb + 0) * FF] = e0;
        eb[(tb + 1) * FF] = e1;
        eb[(tb + 2) * FF] = e2;
        eb[(tb + 3) * FF] = e3;
        esum += (e0 + e1) + (e2 + e3);
    }
    red[ts * FF + f] = esum;
    __syncthreads();
    if (ts == 0) {
        float tot = red[f] + red[FF + f] + red[2 * FF + f] + red[3 * FF + f];
        atomicAdd(&sumexp[b * FF + f], tot);
    }
}

// ---------------- Kernel 2: softmax+pos pack -> bf16 planes in LDS -> MFMA GEMM
// SMALL LOOP BODY (R6 lesson: fully-unrolled ~30 KB body thrashed the 32 KB L1I
// -> all pipes <52% with no memory pressure). nt loop dynamic; 12-MFMA chain
// split into two independent 6-chains (acc1/acc2) for in-iteration ILP.
// PLAIN __launch_bounds__ — min-waves arg clamps VGPR to 64 + spills (R1/R4).
__global__ __launch_bounds__(512) void k_main(
        const unsigned short* __restrict__ Wt,
        const float* __restrict__ db,  const float* __restrict__ sumexp,
        float* __restrict__ shiftsum) {
    __shared__ __align__(16) unsigned short As[16384];   // 32 KB: hi | lo planes

    const int tid = threadIdx.x;
    const int b  = blockIdx.y;
    const int t0 = blockIdx.x * 128;
    const int f = tid & 63, tq = tid >> 6;   // tq in 0..7

    const float inv_se = 1.0f / sumexp[b * FF + f];
    const float tsf = exp2f(-0.20762050586796017f * (float)(f & ~1));
    const int kfh = ((f >> 4) << 1) | ((f >> 3) & 1);   // kf*2 + half
    const int jj  = f & 7;
    // pos encoding: one precise sincos, then rotate by dA = 8*tsf (drift ~2e-6)
    const float ang0 = (float)(t0 + tq) * tsf;
    const float dA = 8.0f * tsf;
    float sv = sinf(ang0), cv = cosf(ang0);
    const float sd = sinf(dA), cd = cosf(dA);

    // phase A: softmax-normalize + pos -> split hi/lo -> As (16 t per thread)
    const float* eb = e_buf + ((size_t)b * TT + t0) * FF + f;
#pragma unroll 4
    for (int i = 0; i < 16; ++i) {
        const int tt = tq + 8 * i;
        float ev = eb[tt * FF];
        float p = (f & 1) ? cv : sv;
        float h = fmaf(ev, inv_se, p);
        const unsigned short hi = f2b(h);
        const unsigned short lo = f2b(h - b2f(hi));
        const int off = ((tt >> 5) * 8 + kfh) * 256 + (tt & 31) * 8 + jj;
        As[off] = hi;
        As[8192 + off] = lo;
        float ns = fmaf(sv, cd, cv * sd);
        float nc = fmaf(cv, cd, -(sv * sd));
        sv = ns; cv = nc;
    }
    __syncthreads();

    // ---- main loop ----
    const int lane = tid & 63;
    const int wv   = tid >> 6;            // 0..7
    const int half = lane >> 5;
    const int ln31 = lane & 31;
    const int vbase = (half << 9) | (ln31 << 4);            // byte offset of lane
    const char* Ab = (const char*)As;
    const char* Wb = (const char*)Wt;

#pragma unroll 1
    for (int i = 0; i < 16; ++i) {
        const int lt = (i + 2 * wv) & 15;   // de-phase waves (bijective coverage)
        const int ltile = lt * 8 + wv;
        const int lbase = ltile * 32;
        const char* wp = Wb + ((size_t)ltile << 12) + vbase;
        short8 Whi[4], Wlo[4];
#pragma unroll
        for (int kf = 0; kf < 4; ++kf) {
            Whi[kf] = *reinterpret_cast<const short8*>(wp + kf * 1024);
            Wlo[kf] = *reinterpret_cast<const short8*>(wp + 524288 + kf * 1024);
        }
        const float dbn = db[lbase + ln31] * (-L2E);   // exp(-z) = exp2(-z*log2e)

        float ss[4] = {0.f, 0.f, 0.f, 0.f};
#pragma unroll 1
        for (int nt = 0; nt < 4; ++nt) {
            const char* ap = Ab + (nt << 12) + vbase;
            floatx16 acc1 = {0.f, 0.f, 0.f, 0.f, 0.f, 0.f, 0.f, 0.f,
                             0.f, 0.f, 0.f, 0.f, 0.f, 0.f, 0.f, 0.f};
            floatx16 acc2 = acc1;
            __builtin_amdgcn_s_setprio(1);
            {   // two independent 6-chains: kf0,1 -> acc1 ; kf2,3 -> acc2
                short8 Ahi = *reinterpret_cast<const short8*>(ap);
                short8 Alo = *reinterpret_cast<const short8*>(ap + 16384);
                acc1 = __builtin_amdgcn_mfma_f32_32x32x16_bf16(Ahi, Whi[0], acc1, 0, 0, 0);
                acc1 = __builtin_amdgcn_mfma_f32_32x32x16_bf16(Alo, Whi[0], acc1, 0, 0, 0);
                acc1 = __builtin_amdgcn_mfma_f32_32x32x16_bf16(Ahi, Wlo[0], acc1, 0, 0, 0);
                Ahi = *reinterpret_cast<const short8*>(ap + 2048);
                Alo = *reinterpret_cast<const short8*>(ap + 16384 + 2048);
                acc2 = __builtin_amdgcn_mfma_f32_32x32x16_bf16(Ahi, Whi[2], acc2, 0, 0, 0);
                acc2 = __builtin_amdgcn_mfma_f32_32x32x16_bf16(Alo, Whi[2], acc2, 0, 0, 0);
                acc2 = __builtin_amdgcn_mfma_f32_32x32x16_bf16(Ahi, Wlo[2], acc2, 0, 0, 0);
                Ahi = *reinterpret_cast<const short8*>(ap + 1024);
                Alo = *reinterpret_cast<const short8*>(ap + 16384 + 1024);
                acc1 = __builtin_amdgcn_mfma_f32_32x32x16_bf16(Ahi, Whi[1], acc1, 0, 0, 0);
                acc1 = __builtin_amdgcn_mfma_f32_32x32x16_bf16(Alo, Whi[1], acc1, 0, 0, 0);
                acc1 = __builtin_amdgcn_mfma_f32_32x32x16_bf16(Ahi, Wlo[1], acc1, 0, 0, 0);
                Ahi = *reinterpret_cast<const short8*>(ap + 3072);
                Alo = *reinterpret_cast<const short8*>(ap + 16384 + 3072);
                acc2 = __builtin_amdgcn_mfma_f32_32x32x16_bf16(Ahi, Whi[3], acc2, 0, 0, 0);
                acc2 = __builtin_amdgcn_mfma_f32_32x32x16_bf16(Alo, Whi[3], acc2, 0, 0, 0);
                acc2 = __builtin_amdgcn_mfma_f32_32x32x16_bf16(Ahi, Wlo[3], acc2, 0, 0, 0);
            }
            __builtin_amdgcn_s_setprio(0);
            // sum of 16 sigmoids, 4-way reciprocal batching:
            // 1/a0+..+1/a3 = ((a0+a1)*a2*a3 + (a2+a3)*a0*a1) / (a0*a1*a2*a3)
#pragma unroll
            for (int q = 0; q < 4; ++q) {
                float e0 = __builtin_amdgcn_exp2f(fmaf(acc1[4 * q + 0], -L2E,
                                                  fmaf(acc2[4 * q + 0], -L2E, dbn)));
                float e1 = __builtin_amdgcn_exp2f(fmaf(acc1[4 * q + 1], -L2E,
                                                  fmaf(acc2[4 * q + 1], -L2E, dbn)));
                float e2 = __builtin_amdgcn_exp2f(fmaf(acc1[4 * q + 2], -L2E,
                                                  fmaf(acc2[4 * q + 2], -L2E, dbn)));
                float e3 = __builtin_amdgcn_exp2f(fmaf(acc1[4 * q + 3], -L2E,
                                                  fmaf(acc2[4 * q + 3], -L2E, dbn)));
                float a0 = 1.f + e0, a1 = 1.f + e1, a2 = 1.f + e2, a3 = 1.f + e3;
                float p01 = a0 * a1, p23 = a2 * a3;
                float num = fmaf(a0 + a1, p23, (a2 + a3) * p01);
                ss[q] = fmaf(num, __builtin_amdgcn_rcpf(p01 * p23), ss[q]);
            }
        }
        float ssum = (ss[0] + ss[1]) + (ss[2] + ss[3]);
        ssum += __shfl_xor(ssum, 32);
        if (half == 0)
            atomicAdd(shiftsum + (size_t)b * LL + lbase + ln31, ssum);
    }
}

// ---------------- Kernel 3: truncated Gaussian warp (shift = 2*S - T) -------------
__global__ __launch_bounds__(256) void k_warp(
        const float* __restrict__ shiftsum, const float* __restrict__ x,
        float* __restrict__ out) {
    const int idx = blockIdx.x * 256 + threadIdx.x;  // = b*L + l
    const int l = idx & (LL - 1);
    const int b = idx >> 12;
    const float sh = fmaf(2.0f, shiftsum[idx], -(float)TT);
    const float scale = (float)TT / (float)LL;
    const float center = ((float)(l + 1) + sh) * scale;
    const float R = 7.0f;
    int tlo = (int)ceilf(center - 1.0f - R);
    int thi = (int)floorf(center - 1.0f + R);
    if (tlo < 0) tlo = 0;
    if (thi > TT - 1) thi = TT - 1;
    float acc[CC];
#pragma unroll
    for (int c = 0; c < CC; ++c) acc[c] = 0.f;
    const float inv_amp = (float)(1.0 / 1.772637204826652);
    for (int t = tlo; t <= thi; ++t) {
        float d = (float)(t + 1) - center;
        float w = __expf(-d * d) * inv_amp;   // WIDTH = 1
        const float4 x0 = *reinterpret_cast<const float4*>(x + ((size_t)b * TT + t) * CC);
        const float4 x1 = *reinterpret_cast<const float4*>(x + ((size_t)b * TT + t) * CC + 4);
        acc[0] = fmaf(w, x0.x, acc[0]);
        acc[1] = fmaf(w, x0.y, acc[1]);
        acc[2] = fmaf(w, x0.z, acc[2]);
        acc[3] = fmaf(w, x0.w, acc[3]);
        acc[4] = fmaf(w, x1.x, acc[4]);
        acc[5] = fmaf(w, x1.y, acc[5]);
        acc[6] = fmaf(w, x1.z, acc[6]);
        acc[7] = fmaf(w, x1.w, acc[7]);
    }
    float* o = out + (size_t)idx * CC;
    *reinterpret_cast<float4*>(o)     = make_float4(acc[0], acc[1], acc[2], acc[3]);
    *reinterpret_cast<float4*>(o + 4) = make_float4(acc[4], acc[5], acc[6], acc[7]);
}

extern "C" void kernel_launch(void* const* d_in, const int* in_sizes, int n_in,
                              void* d_out, int out_size, void* d_ws, size_t ws_size,
                              hipStream_t stream) {
    const float* x  = (const float*)d_in[0];
    const float* cw = (const float*)d_in[1];
    const float* cb = (const float*)d_in[2];
    const float* gm = (const float*)d_in[3];
    const float* bt = (const float*)d_in[4];
    const float* mn = (const float*)d_in[5];
    const float* vr = (const float*)d_in[6];
    const float* dw = (const float*)d_in[7];
    const float* db = (const float*)d_in[8];

    float* sumexp      = (float*)d_ws;                        // 1024 floats
    float* shiftsum    = sumexp + BB * FF;                    // 65536 floats
    unsigned short* Wt = (unsigned short*)(shiftsum + BB * LL); // 524288 ushorts (1 MB)

    hipMemsetAsync(sumexp, 0, (size_t)(BB * FF + BB * LL) * sizeof(float), stream);

    k_convsplit<<<NCONV + (FF * LL) / 256, 256, 0, stream>>>(
        x, cw, cb, gm, bt, mn, vr, dw, Wt, sumexp);
    k_main<<<dim3(TT / 128, BB), 512, 0, stream>>>(Wt, db, sumexp, shiftsum);
    k_warp<<<(BB * LL) / 256, 256, 0, stream>>>(shiftsum, x, (float*)d_out);
}

// Round 8
// 190.335 us; speedup vs baseline: 1.1054x; 1.1054x over previous
//
#include <hip/hip_runtime.h>
#include <stdint.h>

#define BB 16
#define TT 4096
#define CC 8
#define FF 64
#define KW 11
#define LL 4096

#define L2E 1.442695040888963f
#define NCONV (BB * (TT / 64))   // 1024 conv blocks

typedef __attribute__((ext_vector_type(8))) short short8;
typedef __attribute__((ext_vector_type(16))) float floatx16;

// device-global staging (d_ws capacity unknown beyond ~1.3 MB proven)
__device__ float e_buf[(size_t)BB * TT * FF];        // exp(conv+BN), 16.8 MB
__device__ float sumpart[NCONV * FF];                // per-64t-block sumexp partials
__device__ float shift_part[(size_t)BB * 32 * LL];   // per-128t-tile sigmoid-sum partials, 8 MB

__device__ __forceinline__ unsigned short f2b(float f) {
    union { float f; uint32_t i; } v; v.f = f;
    uint32_t x = v.i;
    return (unsigned short)((x + 0x7fffu + ((x >> 16) & 1u)) >> 16);  // RNE
}
__device__ __forceinline__ float b2f(unsigned short u) {
    union { uint32_t i; float f; } v; v.i = ((uint32_t)u) << 16; return v.f;
}

#define DOT8(acc, ra, rb, wp) \
    acc = fmaf(ra.x, (wp)[0], acc); acc = fmaf(ra.y, (wp)[1], acc); \
    acc = fmaf(ra.z, (wp)[2], acc); acc = fmaf(ra.w, (wp)[3], acc); \
    acc = fmaf(rb.x, (wp)[4], acc); acc = fmaf(rb.y, (wp)[5], acc); \
    acc = fmaf(rb.z, (wp)[6], acc); acc = fmaf(rb.w, (wp)[7], acc);

// ---------------- Kernel 1 (fused): blocks [0,NCONV): conv1d+BN+exp -> e_buf +
// sumpart (NON-atomic). blocks [NCONV,NCONV+1024): W * (-log2 e) -> Whi/Wlo bf16
// planes, fragment-linear [ltile 128][kf 4][half 2][ln 32][j 8].
// W pre-scaled so the MFMA emits the exp2 argument directly (R8).
__global__ __launch_bounds__(256) void k_convsplit(
        const float* __restrict__ x, const float* __restrict__ cw,
        const float* __restrict__ cb, const float* __restrict__ gm,
        const float* __restrict__ bt, const float* __restrict__ mn,
        const float* __restrict__ vr, const float* __restrict__ dw,
        unsigned short* __restrict__ Wt) {
    if (blockIdx.x >= NCONV) {
        const int idx  = (blockIdx.x - NCONV) * 256 + threadIdx.x;   // 262144
        const int j    = idx & 7;
        const int ln   = (idx >> 3) & 31;
        const int half = (idx >> 8) & 1;
        const int kf   = (idx >> 9) & 3;
        const int lt   = idx >> 11;
        const int l = lt * 32 + ln;
        const int k = kf * 16 + half * 8 + j;
        const float v = dw[(size_t)k * LL + l] * (-L2E);   // pre-scale by -log2(e)
        const unsigned short hi = f2b(v);
        const unsigned short lo = f2b(v - b2f(hi));
        Wt[idx] = hi;
        Wt[262144 + idx] = lo;
        return;
    }
    // ---- conv part (rolling 4-output window: 28 row-reads per 4 outputs) ----
    __shared__ __align__(16) float xsm[(64 + KW - 1) * CC];   // 592 floats
    __shared__ float red[4 * FF];
    const int tid = threadIdx.x;
    const int b  = blockIdx.x / (TT / 64);
    const int t0 = (blockIdx.x % (TT / 64)) * 64;
    const int f = tid & 63, ts = tid >> 6;

    float wreg[KW * CC];
#pragma unroll
    for (int kc = 0; kc < KW * CC; ++kc) wreg[kc] = cw[kc * FF + f];

    for (int i = tid; i < (64 + KW - 1) * CC; i += 256) {
        int row = i >> 3, c = i & 7;
        int t = t0 - (KW / 2) + row;
        xsm[i] = (t >= 0 && t < TT) ? x[((size_t)b * TT + t) * CC + c] : 0.0f;
    }
    const float s  = gm[f] * rsqrtf(vr[f] + 1e-3f);
    const float bb = bt[f] + (cb[f] - mn[f]) * s;
    const float s2 = s * L2E, b2 = bb * L2E;   // exp(z) = exp2(z*log2e)
    __syncthreads();

    float* eb = e_buf + ((size_t)b * TT + t0) * FF + f;
    const float4* xv = (const float4*)xsm;
    float esum = 0.f;
#pragma unroll 1
    for (int c = 0; c < 4; ++c) {
        const int tb = c * 16 + ts * 4;   // 4 consecutive outputs tb..tb+3
        float a0 = 0.f, a1 = 0.f, a2 = 0.f, a3 = 0.f;
#pragma unroll
        for (int k = 0; k < KW + 3; ++k) {   // rows tb..tb+13 (k compile-time)
            const float4 ra = xv[(tb + k) * 2];
            const float4 rb = xv[(tb + k) * 2 + 1];
            if (k <= 10)           { DOT8(a0, ra, rb, wreg + k * 8); }
            if (k >= 1 && k <= 11) { DOT8(a1, ra, rb, wreg + (k - 1) * 8); }
            if (k >= 2 && k <= 12) { DOT8(a2, ra, rb, wreg + (k - 2) * 8); }
            if (k >= 3)            { DOT8(a3, ra, rb, wreg + (k - 3) * 8); }
        }
        float e0 = __builtin_amdgcn_exp2f(fmaf(a0, s2, b2));
        float e1 = __builtin_amdgcn_exp2f(fmaf(a1, s2, b2));
        float e2 = __builtin_amdgcn_exp2f(fmaf(a2, s2, b2));
        float e3 = __builtin_amdgcn_exp2f(fmaf(a3, s2, b2));
        eb[(tb + 0) * FF] = e0;
        eb[(tb + 1) * FF] = e1;
        eb[(tb + 2) * FF] = e2;
        eb[(tb + 3) * FF] = e3;
        esum += (e0 + e1) + (e2 + e3);
    }
    red[ts * FF + f] = esum;
    __syncthreads();
    if (ts == 0)
        sumpart[blockIdx.x * FF + f] = red[f] + red[FF + f] + red[2 * FF + f] + red[3 * FF + f];
}

// ---------------- Kernel 2: softmax+pos pack -> bf16 planes in LDS -> MFMA GEMM
// R6-proven body (unrolled nt, single 12-MFMA chain). R8: W pre-scaled by -L2E
// and acc initialized to dbn (lane-constant across regs: col=lane&31) so the
// MFMA output IS the exp2 argument — zero per-value arg VALU. Plain stores to
// shift_part (no atomics). PLAIN __launch_bounds__ (min-waves arg => 64-VGPR
// clamp + spill, measured R1/R4).
__global__ __launch_bounds__(512) void k_main(
        const unsigned short* __restrict__ Wt,
        const float* __restrict__ db, float* __restrict__ dummy) {
    __shared__ __align__(16) unsigned short As[16384];   // 32 KB: hi | lo planes

    const int tid = threadIdx.x;
    const int b  = blockIdx.y;
    const int t0 = blockIdx.x * 128;
    const int f = tid & 63, tq = tid >> 6;   // tq in 0..7

    // sumexp reduce: 64 L1-broadcast partials per f (redundant across tq groups)
    float se = 0.f;
    const float* sp = sumpart + (size_t)b * 64 * FF + f;
#pragma unroll 8
    for (int j = 0; j < 64; ++j) se += sp[j * FF];
    const float inv_se = 1.0f / se;

    const float tsf = exp2f(-0.20762050586796017f * (float)(f & ~1));
    const int kfh = ((f >> 4) << 1) | ((f >> 3) & 1);   // kf*2 + half
    const int jj  = f & 7;
    // pos encoding: one precise sincos, then rotate by dA = 8*tsf (drift ~2e-6)
    const float ang0 = (float)(t0 + tq) * tsf;
    const float dA = 8.0f * tsf;
    float sv = sinf(ang0), cv = cosf(ang0);
    const float sd = sinf(dA), cd = cosf(dA);

    // phase A: softmax-normalize + pos -> split hi/lo -> As (16 t per thread)
    const float* eb = e_buf + ((size_t)b * TT + t0) * FF + f;
#pragma unroll 4
    for (int i = 0; i < 16; ++i) {
        const int tt = tq + 8 * i;
        float ev = eb[tt * FF];
        float p = (f & 1) ? cv : sv;
        float h = fmaf(ev, inv_se, p);
        const unsigned short hi = f2b(h);
        const unsigned short lo = f2b(h - b2f(hi));
        const int off = ((tt >> 5) * 8 + kfh) * 256 + (tt & 31) * 8 + jj;
        As[off] = hi;
        As[8192 + off] = lo;
        float ns = fmaf(sv, cd, cv * sd);
        float nc = fmaf(cv, cd, -(sv * sd));
        sv = ns; cv = nc;
    }
    __syncthreads();

    // ---- main loop (no barriers) ----
    const int lane = tid & 63;
    const int wv   = tid >> 6;            // 0..7
    const int half = lane >> 5;
    const int ln31 = lane & 31;
    const int vbase = (half << 9) | (ln31 << 4);            // byte offset of lane
    const char* Ab = (const char*)As;
    const char* Wb = (const char*)Wt;

#pragma unroll 1
    for (int i = 0; i < 16; ++i) {
        const int lt = (i + 2 * wv) & 15;   // de-phase waves (bijective coverage)
        const int ltile = lt * 8 + wv;
        const int lbase = ltile * 32;
        const char* wp = Wb + ((size_t)ltile << 12) + vbase;
        short8 Whi[4], Wlo[4];
#pragma unroll
        for (int kf = 0; kf < 4; ++kf) {
            Whi[kf] = *reinterpret_cast<const short8*>(wp + kf * 1024);
            Wlo[kf] = *reinterpret_cast<const short8*>(wp + 524288 + kf * 1024);
        }
        const float dbn = db[lbase + ln31] * (-L2E);   // exp(-z) = exp2(-L2E*z)

        float ss[4] = {0.f, 0.f, 0.f, 0.f};
#pragma unroll
        for (int nt = 0; nt < 4; ++nt) {
            floatx16 acc;
#pragma unroll
            for (int r = 0; r < 16; ++r) acc[r] = dbn;   // C-init = bias term
            __builtin_amdgcn_s_setprio(1);
#pragma unroll
            for (int kf = 0; kf < 4; ++kf) {
                const int ao = (nt * 8 + kf * 2) << 9;
                short8 Ahi = *reinterpret_cast<const short8*>(Ab + ao + vbase);
                short8 Alo = *reinterpret_cast<const short8*>(Ab + 16384 + ao + vbase);
                acc = __builtin_amdgcn_mfma_f32_32x32x16_bf16(Ahi, Whi[kf], acc, 0, 0, 0);
                acc = __builtin_amdgcn_mfma_f32_32x32x16_bf16(Alo, Whi[kf], acc, 0, 0, 0);
                acc = __builtin_amdgcn_mfma_f32_32x32x16_bf16(Ahi, Wlo[kf], acc, 0, 0, 0);
            }
            __builtin_amdgcn_s_setprio(0);
            // acc[r] IS -L2E*(z+db): e = exp2(acc). 4-way reciprocal batching:
            // 1/a0+..+1/a3 = ((a0+a1)*a2*a3 + (a2+a3)*a0*a1) / (a0*a1*a2*a3)
#pragma unroll
            for (int q = 0; q < 4; ++q) {
                float e0 = __builtin_amdgcn_exp2f(acc[4 * q + 0]);
                float e1 = __builtin_amdgcn_exp2f(acc[4 * q + 1]);
                float e2 = __builtin_amdgcn_exp2f(acc[4 * q + 2]);
                float e3 = __builtin_amdgcn_exp2f(acc[4 * q + 3]);
                float a0 = 1.f + e0, a1 = 1.f + e1, a2 = 1.f + e2, a3 = 1.f + e3;
                float p01 = a0 * a1, p23 = a2 * a3;
                float num = fmaf(a0 + a1, p23, (a2 + a3) * p01);
                ss[q] = fmaf(num, __builtin_amdgcn_rcpf(p01 * p23), ss[q]);
            }
        }
        float ssum = (ss[0] + ss[1]) + (ss[2] + ss[3]);
        ssum += __shfl_xor(ssum, 32);
        if (half == 0)
            shift_part[((size_t)b * 32 + blockIdx.x) * LL + lbase + ln31] = ssum;
    }
}

// ---------------- Kernel 3: truncated Gaussian warp (shift = 2*S - T) -------------
__global__ __launch_bounds__(256) void k_warp(
        const float* __restrict__ x, float* __restrict__ out) {
    const int idx = blockIdx.x * 256 + threadIdx.x;  // = b*L + l
    const int l = idx & (LL - 1);
    const int b = idx >> 12;
    float S = 0.f;
    const float* sp = shift_part + (size_t)b * 32 * LL + l;
#pragma unroll 8
    for (int tt = 0; tt < 32; ++tt) S += sp[tt * LL];
    const float sh = fmaf(2.0f, S, -(float)TT);
    const float scale = (float)TT / (float)LL;
    const float center = ((float)(l + 1) + sh) * scale;
    const float R = 7.0f;
    int tlo = (int)ceilf(center - 1.0f - R);
    int thi = (int)floorf(center - 1.0f + R);
    if (tlo < 0) tlo = 0;
    if (thi > TT - 1) thi = TT - 1;
    float acc[CC];
#pragma unroll
    for (int c = 0; c < CC; ++c) acc[c] = 0.f;
    const float inv_amp = (float)(1.0 / 1.772637204826652);
    for (int t = tlo; t <= thi; ++t) {
        float d = (float)(t + 1) - center;
        float w = __expf(-d * d) * inv_amp;   // WIDTH = 1
        const float4 x0 = *reinterpret_cast<const float4*>(x + ((size_t)b * TT + t) * CC);
        const float4 x1 = *reinterpret_cast<const float4*>(x + ((size_t)b * TT + t) * CC + 4);
        acc[0] = fmaf(w, x0.x, acc[0]);
        acc[1] = fmaf(w, x0.y, acc[1]);
        acc[2] = fmaf(w, x0.z, acc[2]);
        acc[3] = fmaf(w, x0.w, acc[3]);
        acc[4] = fmaf(w, x1.x, acc[4]);
        acc[5] = fmaf(w, x1.y, acc[5]);
        acc[6] = fmaf(w, x1.z, acc[6]);
        acc[7] = fmaf(w, x1.w, acc[7]);
    }
    float* o = out + (size_t)idx * CC;
    *reinterpret_cast<float4*>(o)     = make_float4(acc[0], acc[1], acc[2], acc[3]);
    *reinterpret_cast<float4*>(o + 4) = make_float4(acc[4], acc[5], acc[6], acc[7]);
}

extern "C" void kernel_launch(void* const* d_in, const int* in_sizes, int n_in,
                              void* d_out, int out_size, void* d_ws, size_t ws_size,
                              hipStream_t stream) {
    const float* x  = (const float*)d_in[0];
    const float* cw = (const float*)d_in[1];
    const float* cb = (const float*)d_in[2];
    const float* gm = (const float*)d_in[3];
    const float* bt = (const float*)d_in[4];
    const float* mn = (const float*)d_in[5];
    const float* vr = (const float*)d_in[6];
    const float* dw = (const float*)d_in[7];
    const float* db = (const float*)d_in[8];

    unsigned short* Wt = (unsigned short*)d_ws;   // 524288 ushorts (1 MB)

    k_convsplit<<<NCONV + (FF * LL) / 256, 256, 0, stream>>>(
        x, cw, cb, gm, bt, mn, vr, dw, Wt);
    k_main<<<dim3(TT / 128, BB), 512, 0, stream>>>(Wt, db, nullptr);
    k_warp<<<(BB * LL) / 256, 256, 0, stream>>>(x, (float*)d_out);
}

// Round 9
// 187.612 us; speedup vs baseline: 1.1215x; 1.0145x over previous
//
#include <hip/hip_runtime.h>
#include <stdint.h>

#define BB 16
#define TT 4096
#define CC 8
#define FF 64
#define KW 11
#define LL 4096

#define L2E 1.442695040888963f
#define NCONV (BB * (TT / 64))   // 1024 conv blocks

typedef __attribute__((ext_vector_type(8))) short short8;
typedef __attribute__((ext_vector_type(16))) float floatx16;

// device-global staging
__device__ float e_buf[(size_t)BB * TT * FF];        // exp(conv+BN), 16.8 MB
__device__ float sumpart[NCONV * FF];                // per-64t-block sumexp partials
__device__ float shift_part[(size_t)BB * 32 * LL];   // per-128t-tile sigmoid-sum partials

__device__ __forceinline__ unsigned short f2b(float f) {
    union { float f; uint32_t i; } v; v.f = f;
    uint32_t x = v.i;
    return (unsigned short)((x + 0x7fffu + ((x >> 16) & 1u)) >> 16);  // RNE
}
__device__ __forceinline__ float b2f(unsigned short u) {
    union { uint32_t i; float f; } v; v.i = ((uint32_t)u) << 16; return v.f;
}

#define DOT8(acc, ra, rb, wp) \
    acc = fmaf(ra.x, (wp)[0], acc); acc = fmaf(ra.y, (wp)[1], acc); \
    acc = fmaf(ra.z, (wp)[2], acc); acc = fmaf(ra.w, (wp)[3], acc); \
    acc = fmaf(rb.x, (wp)[4], acc); acc = fmaf(rb.y, (wp)[5], acc); \
    acc = fmaf(rb.z, (wp)[6], acc); acc = fmaf(rb.w, (wp)[7], acc);

// ---------------- Kernel 1 (fused): conv+BN+exp -> e_buf + sumpart; W*-L2E split.
__global__ __launch_bounds__(256) void k_convsplit(
        const float* __restrict__ x, const float* __restrict__ cw,
        const float* __restrict__ cb, const float* __restrict__ gm,
        const float* __restrict__ bt, const float* __restrict__ mn,
        const float* __restrict__ vr, const float* __restrict__ dw,
        unsigned short* __restrict__ Wt) {
    if (blockIdx.x >= NCONV) {
        const int idx  = (blockIdx.x - NCONV) * 256 + threadIdx.x;   // 262144
        const int j    = idx & 7;
        const int ln   = (idx >> 3) & 31;
        const int half = (idx >> 8) & 1;
        const int kf   = (idx >> 9) & 3;
        const int lt   = idx >> 11;
        const int l = lt * 32 + ln;
        const int k = kf * 16 + half * 8 + j;
        const float v = dw[(size_t)k * LL + l] * (-L2E);   // pre-scale by -log2(e)
        const unsigned short hi = f2b(v);
        const unsigned short lo = f2b(v - b2f(hi));
        Wt[idx] = hi;
        Wt[262144 + idx] = lo;
        return;
    }
    __shared__ __align__(16) float xsm[(64 + KW - 1) * CC];
    __shared__ float red[4 * FF];
    const int tid = threadIdx.x;
    const int b  = blockIdx.x / (TT / 64);
    const int t0 = (blockIdx.x % (TT / 64)) * 64;
    const int f = tid & 63, ts = tid >> 6;

    float wreg[KW * CC];
#pragma unroll
    for (int kc = 0; kc < KW * CC; ++kc) wreg[kc] = cw[kc * FF + f];

    for (int i = tid; i < (64 + KW - 1) * CC; i += 256) {
        int row = i >> 3, c = i & 7;
        int t = t0 - (KW / 2) + row;
        xsm[i] = (t >= 0 && t < TT) ? x[((size_t)b * TT + t) * CC + c] : 0.0f;
    }
    const float s  = gm[f] * rsqrtf(vr[f] + 1e-3f);
    const float bb = bt[f] + (cb[f] - mn[f]) * s;
    const float s2 = s * L2E, b2 = bb * L2E;
    __syncthreads();

    float* eb = e_buf + ((size_t)b * TT + t0) * FF + f;
    const float4* xv = (const float4*)xsm;
    float esum = 0.f;
#pragma unroll 1
    for (int c = 0; c < 4; ++c) {
        const int tb = c * 16 + ts * 4;
        float a0 = 0.f, a1 = 0.f, a2 = 0.f, a3 = 0.f;
#pragma unroll
        for (int k = 0; k < KW + 3; ++k) {
            const float4 ra = xv[(tb + k) * 2];
            const float4 rb = xv[(tb + k) * 2 + 1];
            if (k <= 10)           { DOT8(a0, ra, rb, wreg + k * 8); }
            if (k >= 1 && k <= 11) { DOT8(a1, ra, rb, wreg + (k - 1) * 8); }
            if (k >= 2 && k <= 12) { DOT8(a2, ra, rb, wreg + (k - 2) * 8); }
            if (k >= 3)            { DOT8(a3, ra, rb, wreg + (k - 3) * 8); }
        }
        float e0 = __builtin_amdgcn_exp2f(fmaf(a0, s2, b2));
        float e1 = __builtin_amdgcn_exp2f(fmaf(a1, s2, b2));
        float e2 = __builtin_amdgcn_exp2f(fmaf(a2, s2, b2));
        float e3 = __builtin_amdgcn_exp2f(fmaf(a3, s2, b2));
        eb[(tb + 0) * FF] = e0;
        eb[(tb + 1) * FF] = e1;
        eb[(tb + 2) * FF] = e2;
        eb[(tb + 3) * FF] = e3;
        esum += (e0 + e1) + (e2 + e3);
    }
    red[ts * FF + f] = esum;
    __syncthreads();
    if (ts == 0)
        sumpart[blockIdx.x * FF + f] = red[f] + red[FF + f] + red[2 * FF + f] + red[3 * FF + f];
}

// sigmoid-sum epilogue: 4-way reciprocal batching over one acc quadrant set
__device__ __forceinline__ void epi(const floatx16 &acc, float *ss) {
#pragma unroll
    for (int q = 0; q < 4; ++q) {
        float e0 = __builtin_amdgcn_exp2f(acc[4 * q + 0]);
        float e1 = __builtin_amdgcn_exp2f(acc[4 * q + 1]);
        float e2 = __builtin_amdgcn_exp2f(acc[4 * q + 2]);
        float e3 = __builtin_amdgcn_exp2f(acc[4 * q + 3]);
        float a0 = 1.f + e0, a1 = 1.f + e1, a2 = 1.f + e2, a3 = 1.f + e3;
        float p01 = a0 * a1, p23 = a2 * a3;
        float num = fmaf(a0 + a1, p23, (a2 + a3) * p01);
        ss[q] = fmaf(num, __builtin_amdgcn_rcpf(p01 * p23), ss[q]);
    }
}

// ---------------- Kernel 2: A-tile HOISTED TO 128 VGPRs (R8 found ~41 µs/CU of
// LDS-pipe busy from per-lt A re-reads — third pipe alongside MFMA 41 / VALU 50).
// (512,1): VGPR cap 256 (measured rule cap=256/min_waves; R1/R4: min=4 -> 64).
// asm pins prevent the R3 rematerialization. In-wave 2-acc software pipeline
// (CHAIN/EPI interleave) overlaps MFMA with epilogue VALU at 2 waves/SIMD.
__global__ __launch_bounds__(512, 1) void k_main(
        const unsigned short* __restrict__ Wt,
        const float* __restrict__ db, float* __restrict__ dummy) {
    __shared__ __align__(16) unsigned short As[16384];   // 32 KB: hi | lo planes

    const int tid = threadIdx.x;
    const int b  = blockIdx.y;
    const int t0 = blockIdx.x * 128;
    const int f = tid & 63, tq = tid >> 6;   // tq in 0..7

    float se = 0.f;
    const float* sp = sumpart + (size_t)b * 64 * FF + f;
#pragma unroll 8
    for (int j = 0; j < 64; ++j) se += sp[j * FF];
    const float inv_se = 1.0f / se;

    const float tsf = exp2f(-0.20762050586796017f * (float)(f & ~1));
    const int kfh = ((f >> 4) << 1) | ((f >> 3) & 1);
    const int jj  = f & 7;
    const float ang0 = (float)(t0 + tq) * tsf;
    const float dA = 8.0f * tsf;
    float sv = sinf(ang0), cv = cosf(ang0);
    const float sd = sinf(dA), cd = cosf(dA);

    // phase A: softmax-normalize + pos -> split hi/lo -> As (16 t per thread)
    const float* eb = e_buf + ((size_t)b * TT + t0) * FF + f;
#pragma unroll 4
    for (int i = 0; i < 16; ++i) {
        const int tt = tq + 8 * i;
        float ev = eb[tt * FF];
        float p = (f & 1) ? cv : sv;
        float h = fmaf(ev, inv_se, p);
        const unsigned short hi = f2b(h);
        const unsigned short lo = f2b(h - b2f(hi));
        const int off = ((tt >> 5) * 8 + kfh) * 256 + (tt & 31) * 8 + jj;
        As[off] = hi;
        As[8192 + off] = lo;
        float ns = fmaf(sv, cd, cv * sd);
        float nc = fmaf(cv, cd, -(sv * sd));
        sv = ns; cv = nc;
    }
    __syncthreads();

    const int lane = tid & 63;
    const int wv   = tid >> 6;
    const int half = lane >> 5;
    const int ln31 = lane & 31;
    const int vbase = (half << 9) | (ln31 << 4);
    const char* Ab = (const char*)As;
    const char* Wb = (const char*)Wt;

    // ---- hoist the ENTIRE A-tile into 128 pinned VGPRs ----
    short8 Af[4][4], Al[4][4];
#pragma unroll
    for (int nt = 0; nt < 4; ++nt)
#pragma unroll
        for (int kf = 0; kf < 4; ++kf) {
            const int ao = (nt * 8 + kf * 2) << 9;
            Af[nt][kf] = *reinterpret_cast<const short8*>(Ab + ao + vbase);
            Al[nt][kf] = *reinterpret_cast<const short8*>(Ab + 16384 + ao + vbase);
            asm volatile("" : "+v"(Af[nt][kf]), "+v"(Al[nt][kf]));
        }

#define MFMA3(ACC, NT, KF) \
    ACC = __builtin_amdgcn_mfma_f32_32x32x16_bf16(Af[NT][KF], Whi[KF], ACC, 0, 0, 0); \
    ACC = __builtin_amdgcn_mfma_f32_32x32x16_bf16(Al[NT][KF], Whi[KF], ACC, 0, 0, 0); \
    ACC = __builtin_amdgcn_mfma_f32_32x32x16_bf16(Af[NT][KF], Wlo[KF], ACC, 0, 0, 0);

#define CHAIN(ACC, NT) \
    { for (int r = 0; r < 16; ++r) ACC[r] = dbn; } \
    __builtin_amdgcn_s_setprio(1); \
    MFMA3(ACC, NT, 0) MFMA3(ACC, NT, 1) MFMA3(ACC, NT, 2) MFMA3(ACC, NT, 3) \
    __builtin_amdgcn_s_setprio(0);

    // ---- main loop: pure-register MFMA chains, zero LDS traffic ----
#pragma unroll 1
    for (int i = 0; i < 16; ++i) {
        const int lt = (i + 2 * wv) & 15;
        const int ltile = lt * 8 + wv;
        const int lbase = ltile * 32;
        const char* wp = Wb + ((size_t)ltile << 12) + vbase;
        short8 Whi[4], Wlo[4];
#pragma unroll
        for (int kf = 0; kf < 4; ++kf) {
            Whi[kf] = *reinterpret_cast<const short8*>(wp + kf * 1024);
            Wlo[kf] = *reinterpret_cast<const short8*>(wp + 524288 + kf * 1024);
        }
        const float dbn = db[lbase + ln31] * (-L2E);   // exp(-z) = exp2(-L2E*z)

        float ss[4] = {0.f, 0.f, 0.f, 0.f};
        floatx16 accA, accB;
        // in-wave software pipeline: chain(nt+1) executes under epi(nt)
        CHAIN(accA, 0)
        CHAIN(accB, 1)
        epi(accA, ss);
        CHAIN(accA, 2)
        epi(accB, ss);
        CHAIN(accB, 3)
        epi(accA, ss);
        epi(accB, ss);

        float ssum = (ss[0] + ss[1]) + (ss[2] + ss[3]);
        ssum += __shfl_xor(ssum, 32);
        if (half == 0)
            shift_part[((size_t)b * 32 + blockIdx.x) * LL + lbase + ln31] = ssum;
    }
#undef CHAIN
#undef MFMA3
}

// ---------------- Kernel 3: truncated Gaussian warp (shift = 2*S - T) -------------
__global__ __launch_bounds__(256) void k_warp(
        const float* __restrict__ x, float* __restrict__ out) {
    const int idx = blockIdx.x * 256 + threadIdx.x;  // = b*L + l
    const int l = idx & (LL - 1);
    const int b = idx >> 12;
    float S = 0.f;
    const float* sp = shift_part + (size_t)b * 32 * LL + l;
#pragma unroll 8
    for (int tt = 0; tt < 32; ++tt) S += sp[tt * LL];
    const float sh = fmaf(2.0f, S, -(float)TT);
    const float scale = (float)TT / (float)LL;
    const float center = ((float)(l + 1) + sh) * scale;
    const float R = 7.0f;
    int tlo = (int)ceilf(center - 1.0f - R);
    int thi = (int)floorf(center - 1.0f + R);
    if (tlo < 0) tlo = 0;
    if (thi > TT - 1) thi = TT - 1;
    float acc[CC];
#pragma unroll
    for (int c = 0; c < CC; ++c) acc[c] = 0.f;
    const float inv_amp = (float)(1.0 / 1.772637204826652);
    for (int t = tlo; t <= thi; ++t) {
        float d = (float)(t + 1) - center;
        float w = __expf(-d * d) * inv_amp;   // WIDTH = 1
        const float4 x0 = *reinterpret_cast<const float4*>(x + ((size_t)b * TT + t) * CC);
        const float4 x1 = *reinterpret_cast<const float4*>(x + ((size_t)b * TT + t) * CC + 4);
        acc[0] = fmaf(w, x0.x, acc[0]);
        acc[1] = fmaf(w, x0.y, acc[1]);
        acc[2] = fmaf(w, x0.z, acc[2]);
        acc[3] = fmaf(w, x0.w, acc[3]);
        acc[4] = fmaf(w, x1.x, acc[4]);
        acc[5] = fmaf(w, x1.y, acc[5]);
        acc[6] = fmaf(w, x1.z, acc[6]);
        acc[7] = fmaf(w, x1.w, acc[7]);
    }
    float* o = out + (size_t)idx * CC;
    *reinterpret_cast<float4*>(o)     = make_float4(acc[0], acc[1], acc[2], acc[3]);
    *reinterpret_cast<float4*>(o + 4) = make_float4(acc[4], acc[5], acc[6], acc[7]);
}

extern "C" void kernel_launch(void* const* d_in, const int* in_sizes, int n_in,
                              void* d_out, int out_size, void* d_ws, size_t ws_size,
                              hipStream_t stream) {
    const float* x  = (const float*)d_in[0];
    const float* cw = (const float*)d_in[1];
    const float* cb = (const float*)d_in[2];
    const float* gm = (const float*)d_in[3];
    const float* bt = (const float*)d_in[4];
    const float* mn = (const float*)d_in[5];
    const float* vr = (const float*)d_in[6];
    const float* dw = (const float*)d_in[7];
    const float* db = (const float*)d_in[8];

    unsigned short* Wt = (unsigned short*)d_ws;   // 524288 ushorts (1 MB)

    k_convsplit<<<NCONV + (FF * LL) / 256, 256, 0, stream>>>(
        x, cw, cb, gm, bt, mn, vr, dw, Wt);
    k_main<<<dim3(TT / 128, BB), 512, 0, stream>>>(Wt, db, nullptr);
    k_warp<<<(BB * LL) / 256, 256, 0, stream>>>(x, (float*)d_out);
}